// Round 20
// baseline (45.108 us; speedup 1.0000x reference)
//
#include <hip/hip_runtime.h>
#include <hip/hip_fp16.h>

#define B_    1024
#define T_    256
#define C_    128
#define LMAX  32
#define DUMP  33
#define RSTR  36                 // lph row stride in halves: [t][36]

__device__ __forceinline__ float readlanef(float v, int l) {
    return __int_as_float(__builtin_amdgcn_readlane(__float_as_int(v), l));
}
__device__ __forceinline__ float readlane0f(float v) {
    return __int_as_float(__builtin_amdgcn_readfirstlane(__float_as_int(v)));
}
template<int CTRL>
__device__ __forceinline__ float dpp0f(float v) {   // bound_ctrl=1: shifted-in = 0
    return __int_as_float(__builtin_amdgcn_update_dpp(0, __float_as_int(v),
                                                      CTRL, 0xF, 0xF, true));
}
template<int CTRL>
__device__ __forceinline__ int dpp0i(int v) {
    return __builtin_amdgcn_update_dpp(0, v, CTRL, 0xF, 0xF, true);
}
// per-32-half sum: lane31 = sum(l0..31), lane63 = sum(l32..63)
__device__ __forceinline__ float halfsum_dpp(float v) {
    v += dpp0f<0x111>(v); v += dpp0f<0x112>(v);
    v += dpp0f<0x114>(v); v += dpp0f<0x118>(v);
    v += dpp0f<0x142>(v);
    return v;
}
__device__ __forceinline__ float halfsum_shfl(float v) {
    #pragma unroll
    for (int off = 16; off; off >>= 1) v += __shfl_xor(v, off);
    return v;
}
__device__ __forceinline__ float wavesum_dpp(float v) {
    v += dpp0f<0x111>(v); v += dpp0f<0x112>(v); v += dpp0f<0x114>(v);
    v += dpp0f<0x118>(v); v += dpp0f<0x142>(v); v += dpp0f<0x143>(v);
    return readlanef(v, 63);
}
__device__ __forceinline__ float wavemax_dpp(float v) {   // v >= 0
    v = fmaxf(v, dpp0f<0x111>(v)); v = fmaxf(v, dpp0f<0x112>(v));
    v = fmaxf(v, dpp0f<0x114>(v)); v = fmaxf(v, dpp0f<0x118>(v));
    v = fmaxf(v, dpp0f<0x142>(v)); v = fmaxf(v, dpp0f<0x143>(v));
    return readlanef(v, 63);
}

// ---------------- linear-domain steps (on raw e = exp(x)) --------------------
template<bool DPP>
__device__ __forceinline__ void fstepL(float& a, float& a64, float p,
                                       int lane, bool skip) {
    float am1, am2;
    if constexpr (DPP) { am1 = dpp0f<0x138>(a); am2 = dpp0f<0x138>(am1); }
    else {
        float s1 = __shfl_up(a, 1), s2 = __shfl_up(a, 2);
        am1 = (lane < 1) ? 0.f : s1;
        am2 = (lane < 2) ? 0.f : s2;
    }
    float a63 = readlanef(a, 63);
    float pb  = readlane0f(p);          // lane0 = slot0 = blank
    float sum = a + am1 + (skip ? am2 : 0.f);
    a64 = (a64 + a63) * pb;
    a   = sum * p;
}
template<bool DPP>
__device__ __forceinline__ void bstepL(float& B, float& b64, float p,
                                       int lane, bool skipT, bool l63) {
    float r1, b2;
    if constexpr (DPP) { r1 = dpp0f<0x130>(B); b2 = dpp0f<0x130>(r1); }
    else {
        float s1 = __shfl_down(B, 1), s2 = __shfl_down(B, 2);
        r1 = (lane < 63) ? s1 : 0.f;
        b2 = (lane < 62) ? s2 : 0.f;
    }
    float bs1 = l63 ? b64 : r1;
    float pb  = readlane0f(p);
    float sum = B + bs1 + (skipT ? b2 : 0.f);
    b64 = b64 * pb;
    B   = sum * p;
}
template<bool DPP>
__device__ __forceinline__ void rescaleL(float& x, float& x64, float& logZ) {
    float m;
    if constexpr (DPP) m = wavemax_dpp(x);
    else {
        float v = x;
        #pragma unroll
        for (int off = 32; off; off >>= 1) v = fmaxf(v, __shfl_xor(v, off));
        m = v;
    }
    m = fmaxf(fmaxf(m, x64), 1e-30f);
    float r = __builtin_amdgcn_rcpf(m);
    x *= r; x64 *= r; logZ += __logf(m);
}

// load 16 consecutive-t values for this lane's slot ([t][36] layout)
#define LOAD16F(dst, tb) { _Pragma("unroll")                                   \
    for (int j = 0; j < 16; ++j)                                               \
        dst[j] = __half2float(gp[(tb + j) * RSTR]); }

// ---------- forward half: t = 0..127, rescale every 8 steps ------------------
template<bool DPP>
__device__ __forceinline__ void fwd_half(const __half* gp, int lane, bool skip,
                                         int L, float& a_o, float& a64_o, float& lz_o) {
    float xA[16], xB[16];
    LOAD16F(xA, 0); LOAD16F(xB, 16);
    float a = (lane == 0 || (lane == 1 && L > 0)) ? xA[0] : 0.f;
    float a64 = 0.f, logZ = 0.f;
    #pragma unroll
    for (int k = 1; k < 8; ++k) fstepL<DPP>(a, a64, xA[k], lane, skip);
    rescaleL<DPP>(a, a64, logZ);
    #pragma unroll
    for (int k = 8; k < 16; ++k) fstepL<DPP>(a, a64, xA[k], lane, skip);
    rescaleL<DPP>(a, a64, logZ);
    for (int c = 1; c <= 5; c += 2) {
        LOAD16F(xA, (c + 1) * 16);
        #pragma unroll
        for (int k = 0; k < 8; ++k) fstepL<DPP>(a, a64, xB[k], lane, skip);
        rescaleL<DPP>(a, a64, logZ);
        #pragma unroll
        for (int k = 8; k < 16; ++k) fstepL<DPP>(a, a64, xB[k], lane, skip);
        rescaleL<DPP>(a, a64, logZ);
        LOAD16F(xB, (c + 2) * 16);
        #pragma unroll
        for (int k = 0; k < 8; ++k) fstepL<DPP>(a, a64, xA[k], lane, skip);
        rescaleL<DPP>(a, a64, logZ);
        #pragma unroll
        for (int k = 8; k < 16; ++k) fstepL<DPP>(a, a64, xA[k], lane, skip);
        rescaleL<DPP>(a, a64, logZ);
    }
    #pragma unroll
    for (int k = 0; k < 8; ++k) fstepL<DPP>(a, a64, xB[k], lane, skip);
    rescaleL<DPP>(a, a64, logZ);
    #pragma unroll
    for (int k = 8; k < 16; ++k) fstepL<DPP>(a, a64, xB[k], lane, skip);
    rescaleL<DPP>(a, a64, logZ);
    a_o = a; a64_o = a64; lz_o = logZ;
}
// ---------- backward half: t = 255 (init) down to 128 ------------------------
template<bool DPP>
__device__ __forceinline__ void bwd_half(const __half* gp, int lane, bool skipT,
                                         int L, float& B_o, float& b64_o, float& lz_o) {
    bool l63 = (lane == 63);
    float xA[16], xB[16];
    LOAD16F(xA, 240); LOAD16F(xB, 224);
    int twoL = 2 * L;
    float p255 = xA[15];
    float B   = ((lane == twoL) || (L > 0 && lane == twoL - 1)) ? p255 : 0.f;
    float b64 = (twoL == 64) ? readlane0f(p255) : 0.f;
    float logZ = 0.f;
    #pragma unroll
    for (int k = 1; k < 8; ++k) bstepL<DPP>(B, b64, xA[15 - k], lane, skipT, l63);
    rescaleL<DPP>(B, b64, logZ);
    #pragma unroll
    for (int k = 8; k < 16; ++k) bstepL<DPP>(B, b64, xA[15 - k], lane, skipT, l63);
    rescaleL<DPP>(B, b64, logZ);
    for (int c = 1; c <= 5; c += 2) {
        LOAD16F(xA, 240 - (c + 1) * 16);
        #pragma unroll
        for (int k = 0; k < 8; ++k) bstepL<DPP>(B, b64, xB[15 - k], lane, skipT, l63);
        rescaleL<DPP>(B, b64, logZ);
        #pragma unroll
        for (int k = 8; k < 16; ++k) bstepL<DPP>(B, b64, xB[15 - k], lane, skipT, l63);
        rescaleL<DPP>(B, b64, logZ);
        LOAD16F(xB, 240 - (c + 2) * 16);
        #pragma unroll
        for (int k = 0; k < 8; ++k) bstepL<DPP>(B, b64, xA[15 - k], lane, skipT, l63);
        rescaleL<DPP>(B, b64, logZ);
        #pragma unroll
        for (int k = 8; k < 16; ++k) bstepL<DPP>(B, b64, xA[15 - k], lane, skipT, l63);
        rescaleL<DPP>(B, b64, logZ);
    }
    #pragma unroll
    for (int k = 0; k < 8; ++k) bstepL<DPP>(B, b64, xB[15 - k], lane, skipT, l63);
    rescaleL<DPP>(B, b64, logZ);
    #pragma unroll
    for (int k = 8; k < 16; ++k) bstepL<DPP>(B, b64, xB[15 - k], lane, skipT, l63);
    rescaleL<DPP>(B, b64, logZ);
    B_o = B; b64_o = b64; lz_o = logZ;
}

// ---------------------------------------------------------------------------
// Fused kernel (single launch): one block (512 thr, 8 waves) per example.
// Phase 1: store RAW e = exp(x) fp16 for own 4 classes + row-sum S_t.
// Phase 2: wave0 fwd / wave1 bwd on raw e; wave2 computes sum(log S_t).
// Mean fused: lane0 atomicAdd(out, lb / B) (out zeroed by async memset).
// ---------------------------------------------------------------------------
__global__ void __launch_bounds__(512) fused_kernel(const float* __restrict__ yp,
                                                    const int* __restrict__ yt,
                                                    float* __restrict__ out) {
    __shared__ __half lph[T_ * RSTR];    // 18,432 B (slots 0..32; 33-35 pad)
    __shared__ __half lphDump[64];       // per-lane dump column
    __shared__ float  Ssum[T_];          // per-row exp-sum
    __shared__ int    firstOwner[128];
    __shared__ int    owner[33];
    __shared__ float  alphaS[65], BS[66];
    __shared__ float  lzA, lzB, SlogS;

    int tid  = threadIdx.x;
    int w    = tid >> 6;
    int lane = tid & 63;
    int li   = lane & 31;
    int b    = blockIdx.x;
    const int* lab = yt + b * LMAX;

    if (tid < 128) firstOwner[tid] = DUMP;

    // runtime DPP probes (wave-uniform; shfl fallback)
    float ptst = halfsum_dpp((float)(lane + 1));
    bool sumok = __all(readlanef(ptst, 31) == 528.0f &&
                       readlanef(ptst, 63) == 1552.0f) != 0;
    int pr = dpp0i<0x138>(lane + 1);
    bool shrok = __all(pr == ((lane == 0) ? 0 : lane)) != 0;
    int pl = dpp0i<0x130>(lane + 1);
    bool shlok = __all(pl == ((lane == 63) ? 0 : lane + 2)) != 0;
    float fsv = wavesum_dpp((float)(lane + 1));
    bool fullok = __all(fsv == 2080.0f) != 0;

    __syncthreads();
    if (tid < 33) {
        int c = (tid == 0) ? (C_ - 1) : min(max(lab[tid - 1], 0), C_ - 1);
        atomicMin(&firstOwner[c], tid);
    }
    __syncthreads();
    if (tid < 33) {
        int c = (tid == 0) ? (C_ - 1) : min(max(lab[tid - 1], 0), C_ - 1);
        owner[tid] = firstOwner[c];
    }
    int s0 = firstOwner[4 * li + 0];
    int s1 = firstOwner[4 * li + 1];
    int s2 = firstOwner[4 * li + 2];
    int s3 = firstOwner[4 * li + 3];
    __half* lp0 = (s0 == DUMP) ? &lphDump[lane] : &lph[s0];
    __half* lp1 = (s1 == DUMP) ? &lphDump[lane] : &lph[s1];
    __half* lp2 = (s2 == DUMP) ? &lphDump[lane] : &lph[s2];
    __half* lp3 = (s3 == DUMP) ? &lphDump[lane] : &lph[s3];
    int st0 = (s0 == DUMP) ? 0 : RSTR;
    int st1 = (s1 == DUMP) ? 0 : RSTR;
    int st2 = (s2 == DUMP) ? 0 : RSTR;
    int st3 = (s3 == DUMP) ? 0 : RSTR;

    // phase 1: wave w streams rows [w*32, w*32+32), 16 chunks of 2 rows
    const float4* srcQ = (const float4*)(yp + ((size_t)b * T_ + w * 32) * C_);
    int rbase = w * 32 + (lane >> 5);

    #define PROC(V, I, HS) {                                                   \
        float e0 = __expf(fminf((V).x, 11.f)), e1 = __expf(fminf((V).y, 11.f));\
        float e2 = __expf(fminf((V).z, 11.f)), e3 = __expf(fminf((V).w, 11.f));\
        int R = rbase + 2 * (I);                                               \
        lp0[R * st0] = __float2half_rn(e0);                                    \
        lp1[R * st1] = __float2half_rn(e1);                                    \
        lp2[R * st2] = __float2half_rn(e2);                                    \
        lp3[R * st3] = __float2half_rn(e3);                                    \
        float tt = HS(e0 + e1 + e2 + e3);                                      \
        if (li == 31) Ssum[R] = tt; }
    #define LOOP(HS) {                                                         \
        float4 u0 = srcQ[lane], u1 = srcQ[64 + lane],                          \
               u2 = srcQ[128 + lane], u3 = srcQ[192 + lane];                   \
        _Pragma("unroll")                                                      \
        for (int ii = 0; ii < 4; ++ii) {                                       \
            float4 n0, n1, n2, n3;                                             \
            if (ii < 3) {                                                      \
                n0 = srcQ[(ii * 4 + 4) * 64 + lane];                           \
                n1 = srcQ[(ii * 4 + 5) * 64 + lane];                           \
                n2 = srcQ[(ii * 4 + 6) * 64 + lane];                           \
                n3 = srcQ[(ii * 4 + 7) * 64 + lane];                           \
            }                                                                  \
            PROC(u0, ii * 4 + 0, HS); PROC(u1, ii * 4 + 1, HS);                \
            PROC(u2, ii * 4 + 2, HS); PROC(u3, ii * 4 + 3, HS);                \
            if (ii < 3) { u0 = n0; u1 = n1; u2 = n2; u3 = n3; }                \
        } }

    if (sumok) LOOP(halfsum_dpp)
    else       LOOP(halfsum_shfl)
    #undef LOOP
    #undef PROC

    __syncthreads();

    // phase 2: wave0 fwd, wave1 bwd, wave2 sum(log S_t); waves 3-7 to barrier
    int myl = (lane < LMAX) ? lab[lane] : 99;
    unsigned long long bal = __ballot(lane < LMAX && myl != 99);
    int L = __popcll(bal);
    int  j2  = lane >> 1;
    bool odd = (lane & 1) != 0;
    int  myslot = odd ? (1 + j2) : 0;

    if (w == 0) {
        __builtin_amdgcn_s_setprio(1);
        const __half* gp = &lph[owner[myslot]];
        bool skip = odd && (lab[j2] != ((j2 > 0) ? lab[j2 - 1] : (C_ - 1)));
        float a, a64, lz;
        if (shrok && fullok) fwd_half<true >(gp, lane, skip, L, a, a64, lz);
        else                 fwd_half<false>(gp, lane, skip, L, a, a64, lz);
        alphaS[lane] = a;
        if (lane == 0) { alphaS[64] = a64; lzA = lz; }
        __builtin_amdgcn_s_setprio(0);
    } else if (w == 1) {
        __builtin_amdgcn_s_setprio(1);
        const __half* gp = &lph[owner[myslot]];
        bool skipT = odd && (lane <= 61) && (lab[min(j2 + 1, 31)] != lab[j2]);
        float Bv, b64, lz;
        if (shlok && fullok) bwd_half<true >(gp, lane, skipT, L, Bv, b64, lz);
        else                 bwd_half<false>(gp, lane, skipT, L, Bv, b64, lz);
        BS[lane] = Bv;
        if (lane == 0) { BS[64] = b64; BS[65] = 0.f; lzB = lz; }
        __builtin_amdgcn_s_setprio(0);
    } else if (w == 2) {
        float s = __logf(Ssum[lane]) + __logf(Ssum[lane + 64])
                + __logf(Ssum[lane + 128]) + __logf(Ssum[lane + 192]);
        float tot;
        if (fullok) tot = wavesum_dpp(s);
        else {
            #pragma unroll
            for (int off = 32; off; off >>= 1) s += __shfl_xor(s, off);
            tot = s;
        }
        if (lane == 0) SlogS = tot;
    }
    __syncthreads();

    if (w == 0) {
        bool skipT = odd && (lane <= 61) && (lab[min(j2 + 1, 31)] != lab[j2]);
        float bex = BS[lane] + BS[lane + 1] + (skipT ? BS[lane + 2] : 0.f);
        float contrib = alphaS[lane] * bex;
        if (lane == 0) contrib += alphaS[64] * BS[64];
        #pragma unroll
        for (int off = 32; off; off >>= 1) contrib += __shfl_xor(contrib, off);
        if (lane == 0) {
            float lb = -(__logf(fmaxf(contrib, 1e-37f)) + lzA + lzB - SlogS);
            atomicAdd(out, lb * (1.0f / B_));
        }
    }
}

extern "C" void kernel_launch(void* const* d_in, const int* in_sizes, int n_in,
                              void* d_out, int out_size, void* d_ws, size_t ws_size,
                              hipStream_t stream) {
    const int*   yt  = (const int*)d_in[0];
    const float* yp  = (const float*)d_in[1];
    float*       out = (float*)d_out;

    hipMemsetAsync(out, 0, sizeof(float), stream);
    fused_kernel<<<B_, 512, 0, stream>>>(yp, yt, out);
}

// Round 21
// 40.017 us; speedup vs baseline: 1.1272x; 1.1272x over previous
//
#include <hip/hip_runtime.h>
#include <hip/hip_fp16.h>

#define B_    1024
#define T_    256
#define C_    128
#define LMAX  32
#define DUMP  33
#define RSTR  36                 // lph row stride in halves: [t][36]

__device__ __forceinline__ float readlanef(float v, int l) {
    return __int_as_float(__builtin_amdgcn_readlane(__float_as_int(v), l));
}
__device__ __forceinline__ float readlane0f(float v) {
    return __int_as_float(__builtin_amdgcn_readfirstlane(__float_as_int(v)));
}
template<int CTRL>
__device__ __forceinline__ float dpp0f(float v) {   // bound_ctrl=1: shifted-in = 0
    return __int_as_float(__builtin_amdgcn_update_dpp(0, __float_as_int(v),
                                                      CTRL, 0xF, 0xF, true));
}
template<int CTRL>
__device__ __forceinline__ int dpp0i(int v) {
    return __builtin_amdgcn_update_dpp(0, v, CTRL, 0xF, 0xF, true);
}
// per-32-half sum: lane31 = sum(l0..31), lane63 = sum(l32..63)
__device__ __forceinline__ float halfsum_dpp(float v) {
    v += dpp0f<0x111>(v); v += dpp0f<0x112>(v);
    v += dpp0f<0x114>(v); v += dpp0f<0x118>(v);
    v += dpp0f<0x142>(v);
    return v;
}
__device__ __forceinline__ float halfsum_shfl(float v) {
    #pragma unroll
    for (int off = 16; off; off >>= 1) v += __shfl_xor(v, off);
    return v;
}
__device__ __forceinline__ float wavesum_dpp(float v) {
    v += dpp0f<0x111>(v); v += dpp0f<0x112>(v); v += dpp0f<0x114>(v);
    v += dpp0f<0x118>(v); v += dpp0f<0x142>(v); v += dpp0f<0x143>(v);
    return readlanef(v, 63);
}
__device__ __forceinline__ float wavemax_dpp(float v) {   // v >= 0
    v = fmaxf(v, dpp0f<0x111>(v)); v = fmaxf(v, dpp0f<0x112>(v));
    v = fmaxf(v, dpp0f<0x114>(v)); v = fmaxf(v, dpp0f<0x118>(v));
    v = fmaxf(v, dpp0f<0x142>(v)); v = fmaxf(v, dpp0f<0x143>(v));
    return readlanef(v, 63);
}

// ---------------- linear-domain steps (on raw e = exp(x)) --------------------
template<bool DPP>
__device__ __forceinline__ void fstepL(float& a, float& a64, float p,
                                       int lane, bool skip) {
    float am1, am2;
    if constexpr (DPP) { am1 = dpp0f<0x138>(a); am2 = dpp0f<0x138>(am1); }
    else {
        float s1 = __shfl_up(a, 1), s2 = __shfl_up(a, 2);
        am1 = (lane < 1) ? 0.f : s1;
        am2 = (lane < 2) ? 0.f : s2;
    }
    float a63 = readlanef(a, 63);
    float pb  = readlane0f(p);          // lane0 = slot0 = blank
    float sum = a + am1 + (skip ? am2 : 0.f);
    a64 = (a64 + a63) * pb;
    a   = sum * p;
}
template<bool DPP>
__device__ __forceinline__ void bstepL(float& B, float& b64, float p,
                                       int lane, bool skipT, bool l63) {
    float r1, b2;
    if constexpr (DPP) { r1 = dpp0f<0x130>(B); b2 = dpp0f<0x130>(r1); }
    else {
        float s1 = __shfl_down(B, 1), s2 = __shfl_down(B, 2);
        r1 = (lane < 63) ? s1 : 0.f;
        b2 = (lane < 62) ? s2 : 0.f;
    }
    float bs1 = l63 ? b64 : r1;
    float pb  = readlane0f(p);
    float sum = B + bs1 + (skipT ? b2 : 0.f);
    b64 = b64 * pb;
    B   = sum * p;
}
template<bool DPP>
__device__ __forceinline__ void rescaleL(float& x, float& x64, float& logZ) {
    float m;
    if constexpr (DPP) m = wavemax_dpp(x);
    else {
        float v = x;
        #pragma unroll
        for (int off = 32; off; off >>= 1) v = fmaxf(v, __shfl_xor(v, off));
        m = v;
    }
    m = fmaxf(fmaxf(m, x64), 1e-30f);
    float r = __builtin_amdgcn_rcpf(m);
    x *= r; x64 *= r; logZ += __logf(m);
}

// load 16 consecutive-t values for this lane's slot ([t][36] layout)
#define LOAD16F(dst, tb) { _Pragma("unroll")                                   \
    for (int j = 0; j < 16; ++j)                                               \
        dst[j] = __half2float(gp[(tb + j) * RSTR]); }

// ---------- forward half: t = 0..127, rescale every 8 steps ------------------
template<bool DPP>
__device__ __forceinline__ void fwd_half(const __half* gp, int lane, bool skip,
                                         int L, float& a_o, float& a64_o, float& lz_o) {
    float xA[16], xB[16];
    LOAD16F(xA, 0); LOAD16F(xB, 16);
    float a = (lane == 0 || (lane == 1 && L > 0)) ? xA[0] : 0.f;
    float a64 = 0.f, logZ = 0.f;
    #pragma unroll
    for (int k = 1; k < 8; ++k) fstepL<DPP>(a, a64, xA[k], lane, skip);
    rescaleL<DPP>(a, a64, logZ);
    #pragma unroll
    for (int k = 8; k < 16; ++k) fstepL<DPP>(a, a64, xA[k], lane, skip);
    rescaleL<DPP>(a, a64, logZ);
    for (int c = 1; c <= 5; c += 2) {
        LOAD16F(xA, (c + 1) * 16);
        #pragma unroll
        for (int k = 0; k < 8; ++k) fstepL<DPP>(a, a64, xB[k], lane, skip);
        rescaleL<DPP>(a, a64, logZ);
        #pragma unroll
        for (int k = 8; k < 16; ++k) fstepL<DPP>(a, a64, xB[k], lane, skip);
        rescaleL<DPP>(a, a64, logZ);
        LOAD16F(xB, (c + 2) * 16);
        #pragma unroll
        for (int k = 0; k < 8; ++k) fstepL<DPP>(a, a64, xA[k], lane, skip);
        rescaleL<DPP>(a, a64, logZ);
        #pragma unroll
        for (int k = 8; k < 16; ++k) fstepL<DPP>(a, a64, xA[k], lane, skip);
        rescaleL<DPP>(a, a64, logZ);
    }
    #pragma unroll
    for (int k = 0; k < 8; ++k) fstepL<DPP>(a, a64, xB[k], lane, skip);
    rescaleL<DPP>(a, a64, logZ);
    #pragma unroll
    for (int k = 8; k < 16; ++k) fstepL<DPP>(a, a64, xB[k], lane, skip);
    rescaleL<DPP>(a, a64, logZ);
    a_o = a; a64_o = a64; lz_o = logZ;
}
// ---------- backward half: t = 255 (init) down to 128 ------------------------
template<bool DPP>
__device__ __forceinline__ void bwd_half(const __half* gp, int lane, bool skipT,
                                         int L, float& B_o, float& b64_o, float& lz_o) {
    bool l63 = (lane == 63);
    float xA[16], xB[16];
    LOAD16F(xA, 240); LOAD16F(xB, 224);
    int twoL = 2 * L;
    float p255 = xA[15];
    float B   = ((lane == twoL) || (L > 0 && lane == twoL - 1)) ? p255 : 0.f;
    float b64 = (twoL == 64) ? readlane0f(p255) : 0.f;
    float logZ = 0.f;
    #pragma unroll
    for (int k = 1; k < 8; ++k) bstepL<DPP>(B, b64, xA[15 - k], lane, skipT, l63);
    rescaleL<DPP>(B, b64, logZ);
    #pragma unroll
    for (int k = 8; k < 16; ++k) bstepL<DPP>(B, b64, xA[15 - k], lane, skipT, l63);
    rescaleL<DPP>(B, b64, logZ);
    for (int c = 1; c <= 5; c += 2) {
        LOAD16F(xA, 240 - (c + 1) * 16);
        #pragma unroll
        for (int k = 0; k < 8; ++k) bstepL<DPP>(B, b64, xB[15 - k], lane, skipT, l63);
        rescaleL<DPP>(B, b64, logZ);
        #pragma unroll
        for (int k = 8; k < 16; ++k) bstepL<DPP>(B, b64, xB[15 - k], lane, skipT, l63);
        rescaleL<DPP>(B, b64, logZ);
        LOAD16F(xB, 240 - (c + 2) * 16);
        #pragma unroll
        for (int k = 0; k < 8; ++k) bstepL<DPP>(B, b64, xA[15 - k], lane, skipT, l63);
        rescaleL<DPP>(B, b64, logZ);
        #pragma unroll
        for (int k = 8; k < 16; ++k) bstepL<DPP>(B, b64, xA[15 - k], lane, skipT, l63);
        rescaleL<DPP>(B, b64, logZ);
    }
    #pragma unroll
    for (int k = 0; k < 8; ++k) bstepL<DPP>(B, b64, xB[15 - k], lane, skipT, l63);
    rescaleL<DPP>(B, b64, logZ);
    #pragma unroll
    for (int k = 8; k < 16; ++k) bstepL<DPP>(B, b64, xB[15 - k], lane, skipT, l63);
    rescaleL<DPP>(B, b64, logZ);
    B_o = B; b64_o = b64; lz_o = logZ;
}

// ---------------------------------------------------------------------------
// Fused kernel: one block (512 thr, 8 waves) per example (R19 / best config).
// Phase 1: store RAW e = exp(x) fp16 for own 4 classes + row-sum S_t.
// Phase 2: wave0 fwd / wave1 bwd on raw e; wave2 computes sum(log S_t).
// Seam: loss = -(log(sum a*Bex + a64*B64) + lzA + lzB - SlogS).
// ---------------------------------------------------------------------------
__global__ void __launch_bounds__(512) fused_kernel(const float* __restrict__ yp,
                                                    const int* __restrict__ yt,
                                                    float* __restrict__ loss) {
    __shared__ __half lph[T_ * RSTR];    // 18,432 B (slots 0..32; 33-35 pad)
    __shared__ __half lphDump[64];       // per-lane dump column
    __shared__ float  Ssum[T_];          // per-row exp-sum
    __shared__ int    firstOwner[128];
    __shared__ int    owner[33];
    __shared__ float  alphaS[65], BS[66];
    __shared__ float  lzA, lzB, SlogS;

    int tid  = threadIdx.x;
    int w    = tid >> 6;
    int lane = tid & 63;
    int li   = lane & 31;
    int b    = blockIdx.x;
    const int* lab = yt + b * LMAX;

    if (tid < 128) firstOwner[tid] = DUMP;

    // runtime DPP probes (wave-uniform; shfl fallback)
    float ptst = halfsum_dpp((float)(lane + 1));
    bool sumok = __all(readlanef(ptst, 31) == 528.0f &&
                       readlanef(ptst, 63) == 1552.0f) != 0;
    int pr = dpp0i<0x138>(lane + 1);
    bool shrok = __all(pr == ((lane == 0) ? 0 : lane)) != 0;
    int pl = dpp0i<0x130>(lane + 1);
    bool shlok = __all(pl == ((lane == 63) ? 0 : lane + 2)) != 0;
    float fsv = wavesum_dpp((float)(lane + 1));
    bool fullok = __all(fsv == 2080.0f) != 0;

    __syncthreads();
    if (tid < 33) {
        int c = (tid == 0) ? (C_ - 1) : min(max(lab[tid - 1], 0), C_ - 1);
        atomicMin(&firstOwner[c], tid);
    }
    __syncthreads();
    if (tid < 33) {
        int c = (tid == 0) ? (C_ - 1) : min(max(lab[tid - 1], 0), C_ - 1);
        owner[tid] = firstOwner[c];
    }
    int s0 = firstOwner[4 * li + 0];
    int s1 = firstOwner[4 * li + 1];
    int s2 = firstOwner[4 * li + 2];
    int s3 = firstOwner[4 * li + 3];
    __half* lp0 = (s0 == DUMP) ? &lphDump[lane] : &lph[s0];
    __half* lp1 = (s1 == DUMP) ? &lphDump[lane] : &lph[s1];
    __half* lp2 = (s2 == DUMP) ? &lphDump[lane] : &lph[s2];
    __half* lp3 = (s3 == DUMP) ? &lphDump[lane] : &lph[s3];
    int st0 = (s0 == DUMP) ? 0 : RSTR;
    int st1 = (s1 == DUMP) ? 0 : RSTR;
    int st2 = (s2 == DUMP) ? 0 : RSTR;
    int st3 = (s3 == DUMP) ? 0 : RSTR;

    // phase 1: wave w streams rows [w*32, w*32+32), 16 chunks of 2 rows
    const float4* srcQ = (const float4*)(yp + ((size_t)b * T_ + w * 32) * C_);
    int rbase = w * 32 + (lane >> 5);

    #define PROC(V, I, HS) {                                                   \
        float e0 = __expf(fminf((V).x, 11.f)), e1 = __expf(fminf((V).y, 11.f));\
        float e2 = __expf(fminf((V).z, 11.f)), e3 = __expf(fminf((V).w, 11.f));\
        int R = rbase + 2 * (I);                                               \
        lp0[R * st0] = __float2half_rn(e0);                                    \
        lp1[R * st1] = __float2half_rn(e1);                                    \
        lp2[R * st2] = __float2half_rn(e2);                                    \
        lp3[R * st3] = __float2half_rn(e3);                                    \
        float tt = HS(e0 + e1 + e2 + e3);                                      \
        if (li == 31) Ssum[R] = tt; }
    #define LOOP(HS) {                                                         \
        float4 u0 = srcQ[lane], u1 = srcQ[64 + lane],                          \
               u2 = srcQ[128 + lane], u3 = srcQ[192 + lane];                   \
        _Pragma("unroll")                                                      \
        for (int ii = 0; ii < 4; ++ii) {                                       \
            float4 n0, n1, n2, n3;                                             \
            if (ii < 3) {                                                      \
                n0 = srcQ[(ii * 4 + 4) * 64 + lane];                           \
                n1 = srcQ[(ii * 4 + 5) * 64 + lane];                           \
                n2 = srcQ[(ii * 4 + 6) * 64 + lane];                           \
                n3 = srcQ[(ii * 4 + 7) * 64 + lane];                           \
            }                                                                  \
            PROC(u0, ii * 4 + 0, HS); PROC(u1, ii * 4 + 1, HS);                \
            PROC(u2, ii * 4 + 2, HS); PROC(u3, ii * 4 + 3, HS);                \
            if (ii < 3) { u0 = n0; u1 = n1; u2 = n2; u3 = n3; }                \
        } }

    if (sumok) LOOP(halfsum_dpp)
    else       LOOP(halfsum_shfl)
    #undef LOOP
    #undef PROC

    __syncthreads();

    // phase 2: wave0 fwd, wave1 bwd, wave2 sum(log S_t); waves 3-7 to barrier
    int myl = (lane < LMAX) ? lab[lane] : 99;
    unsigned long long bal = __ballot(lane < LMAX && myl != 99);
    int L = __popcll(bal);
    int  j2  = lane >> 1;
    bool odd = (lane & 1) != 0;
    int  myslot = odd ? (1 + j2) : 0;

    if (w == 0) {
        __builtin_amdgcn_s_setprio(1);
        const __half* gp = &lph[owner[myslot]];
        bool skip = odd && (lab[j2] != ((j2 > 0) ? lab[j2 - 1] : (C_ - 1)));
        float a, a64, lz;
        if (shrok && fullok) fwd_half<true >(gp, lane, skip, L, a, a64, lz);
        else                 fwd_half<false>(gp, lane, skip, L, a, a64, lz);
        alphaS[lane] = a;
        if (lane == 0) { alphaS[64] = a64; lzA = lz; }
        __builtin_amdgcn_s_setprio(0);
    } else if (w == 1) {
        __builtin_amdgcn_s_setprio(1);
        const __half* gp = &lph[owner[myslot]];
        bool skipT = odd && (lane <= 61) && (lab[min(j2 + 1, 31)] != lab[j2]);
        float Bv, b64, lz;
        if (shlok && fullok) bwd_half<true >(gp, lane, skipT, L, Bv, b64, lz);
        else                 bwd_half<false>(gp, lane, skipT, L, Bv, b64, lz);
        BS[lane] = Bv;
        if (lane == 0) { BS[64] = b64; BS[65] = 0.f; lzB = lz; }
        __builtin_amdgcn_s_setprio(0);
    } else if (w == 2) {
        float s = __logf(Ssum[lane]) + __logf(Ssum[lane + 64])
                + __logf(Ssum[lane + 128]) + __logf(Ssum[lane + 192]);
        float tot;
        if (fullok) tot = wavesum_dpp(s);
        else {
            #pragma unroll
            for (int off = 32; off; off >>= 1) s += __shfl_xor(s, off);
            tot = s;
        }
        if (lane == 0) SlogS = tot;
    }
    __syncthreads();

    if (w == 0) {
        bool skipT = odd && (lane <= 61) && (lab[min(j2 + 1, 31)] != lab[j2]);
        float bex = BS[lane] + BS[lane + 1] + (skipT ? BS[lane + 2] : 0.f);
        float contrib = alphaS[lane] * bex;
        if (lane == 0) contrib += alphaS[64] * BS[64];
        #pragma unroll
        for (int off = 32; off; off >>= 1) contrib += __shfl_xor(contrib, off);
        if (lane == 0)
            loss[b] = -(__logf(fmaxf(contrib, 1e-37f)) + lzA + lzB - SlogS);
    }
}

// ---------------------------------------------------------------------------
// mean of per-example losses -> d_out[0]
// ---------------------------------------------------------------------------
__global__ void __launch_bounds__(256) reduce_kernel(const float* __restrict__ loss,
                                                     float* __restrict__ out) {
    __shared__ float ps[4];
    int t = threadIdx.x;
    float4 v = ((const float4*)loss)[t];
    float s = v.x + v.y + v.z + v.w;
    #pragma unroll
    for (int off = 32; off; off >>= 1) s += __shfl_xor(s, off);
    if ((t & 63) == 0) ps[t >> 6] = s;
    __syncthreads();
    if (t == 0) out[0] = (ps[0] + ps[1] + ps[2] + ps[3]) * (1.0f / B_);
}

extern "C" void kernel_launch(void* const* d_in, const int* in_sizes, int n_in,
                              void* d_out, int out_size, void* d_ws, size_t ws_size,
                              hipStream_t stream) {
    const int*   yt  = (const int*)d_in[0];
    const float* yp  = (const float*)d_in[1];
    float*       out = (float*)d_out;
    float*       loss = (float*)d_ws;          // [B] floats

    fused_kernel<<<B_, 512, 0, stream>>>(yp, yt, loss);
    reduce_kernel<<<1, 256, 0, stream>>>(loss, out);
}